// Round 1
// baseline (1651.622 us; speedup 1.0000x reference)
//
#include <hip/hip_runtime.h>
#include <hip/hip_bf16.h>

// ---------------------------------------------------------------------------
// GAT (2 GATConv layers + 5-layer MLP head), fp32, CSR-based edge softmax.
// ---------------------------------------------------------------------------

#define TILE 64
#define KC 16

// Generic fp32 GEMM: C[M x Nc] = A[M x 128] @ W[128 x Nc]  (+bias, +lrelu0.01)
// flags: 1 = add bias, 2 = leaky_relu(0.01)
__global__ __launch_bounds__(256) void gemm_kernel(
    const float* __restrict__ A, const float* __restrict__ W,
    const float* __restrict__ bias, float* __restrict__ C,
    int M, int Nc, int K, int flags)
{
    __shared__ float As[KC][TILE];   // [k][row]
    __shared__ float Ws[KC][TILE];   // [k][col]
    int tid = threadIdx.x;
    int tx = tid & 15, ty = tid >> 4;
    int rowBase = blockIdx.x * TILE;
    int colBase = blockIdx.y * TILE;
    float acc[4][4] = {};

    int la_r = tid >> 2;           // 0..63 tile row
    int la_c = (tid & 3) * 4;      // 0,4,8,12 k offset
    int lw_r = tid >> 4;           // 0..15 k row
    int lw_c = (tid & 15) * 4;     // 0..60 col offset
    bool ncAligned = ((Nc & 3) == 0);

    for (int k0 = 0; k0 < K; k0 += KC) {
        // --- load A tile (64 rows x 16 k), transpose into As[k][row]
        float4 av = make_float4(0.f, 0.f, 0.f, 0.f);
        int arow = rowBase + la_r;
        if (arow < M)
            av = *(const float4*)(A + (size_t)arow * K + k0 + la_c);
        As[la_c + 0][la_r] = av.x;
        As[la_c + 1][la_r] = av.y;
        As[la_c + 2][la_r] = av.z;
        As[la_c + 3][la_r] = av.w;
        // --- load W tile (16 k x 64 cols)
        float4 wv = make_float4(0.f, 0.f, 0.f, 0.f);
        int wc = colBase + lw_c;
        const float* wrow = W + (size_t)(k0 + lw_r) * Nc;
        if (ncAligned && wc + 3 < Nc) {
            wv = *(const float4*)(wrow + wc);
        } else {
            float t0 = (wc + 0 < Nc) ? wrow[wc + 0] : 0.f;
            float t1 = (wc + 1 < Nc) ? wrow[wc + 1] : 0.f;
            float t2 = (wc + 2 < Nc) ? wrow[wc + 2] : 0.f;
            float t3 = (wc + 3 < Nc) ? wrow[wc + 3] : 0.f;
            wv = make_float4(t0, t1, t2, t3);
        }
        *(float4*)&Ws[lw_r][lw_c] = wv;
        __syncthreads();
        #pragma unroll
        for (int kk = 0; kk < KC; ++kk) {
            float a[4], b[4];
            *(float4*)a = *(const float4*)&As[kk][ty * 4];
            *(float4*)b = *(const float4*)&Ws[kk][tx * 4];
            #pragma unroll
            for (int i = 0; i < 4; ++i)
                #pragma unroll
                for (int j = 0; j < 4; ++j)
                    acc[i][j] += a[i] * b[j];
        }
        __syncthreads();
    }
    // epilogue
    #pragma unroll
    for (int i = 0; i < 4; ++i) {
        int r = rowBase + ty * 4 + i;
        if (r >= M) continue;
        #pragma unroll
        for (int j = 0; j < 4; ++j) {
            int c = colBase + tx * 4 + j;
            if (c >= Nc) continue;
            float v = acc[i][j];
            if (flags & 1) v += bias[c];
            if (flags & 2) v = (v < 0.f) ? 0.01f * v : v;
            C[(size_t)r * Nc + c] = v;
        }
    }
}

// el[n,h] = dot(h[n,h,:], al[h,:]); er likewise. h is N x 384.
__global__ __launch_bounds__(384) void eler_kernel(
    const float* __restrict__ h, const float* __restrict__ al,
    const float* __restrict__ ar, float* __restrict__ el,
    float* __restrict__ er, int N)
{
    int n = blockIdx.x;
    int tid = threadIdx.x;
    int hh = tid >> 7;
    int f = tid & 127;
    float x = h[(size_t)n * 384 + tid];
    __shared__ float sl[384], sr[384];
    sl[tid] = x * al[tid];
    sr[tid] = x * ar[tid];
    __syncthreads();
    for (int s = 64; s > 0; s >>= 1) {
        if (f < s) { sl[tid] += sl[tid + s]; sr[tid] += sr[tid + s]; }
        __syncthreads();
    }
    if (f == 0) {
        el[n * 3 + hh] = sl[tid];
        er[n * 3 + hh] = sr[tid];
    }
}

// CSR build: histogram of dst
__global__ void hist_kernel(const int* __restrict__ dst, int* __restrict__ cnt, int E)
{
    int e = blockIdx.x * blockDim.x + threadIdx.x;
    if (e < E) atomicAdd(&cnt[dst[e]], 1);
}

// Single-block exclusive scan: off[0..n] from cnt[0..n-1]
__global__ __launch_bounds__(1024) void scan_kernel(const int* __restrict__ cnt,
                                                    int* __restrict__ off, int n)
{
    __shared__ int carry;
    __shared__ int tmp[1024];
    if (threadIdx.x == 0) carry = 0;
    __syncthreads();
    for (int base = 0; base < n; base += 1024) {
        int i = base + threadIdx.x;
        int v = (i < n) ? cnt[i] : 0;
        tmp[threadIdx.x] = v;
        __syncthreads();
        for (int s = 1; s < 1024; s <<= 1) {
            int t = (threadIdx.x >= s) ? tmp[threadIdx.x - s] : 0;
            __syncthreads();
            tmp[threadIdx.x] += t;
            __syncthreads();
        }
        int excl = tmp[threadIdx.x] - v;
        if (i < n) off[i] = carry + excl;
        __syncthreads();
        if (threadIdx.x == 1023) carry += tmp[1023];
        __syncthreads();
    }
    if (threadIdx.x == 0) off[n] = carry;
}

// scatter edges into dst-sorted CSR (store src id)
__global__ void scatter_kernel(const int* __restrict__ src, const int* __restrict__ dst,
                               const int* __restrict__ off, int* __restrict__ pcnt,
                               int* __restrict__ csrc, int E)
{
    int e = blockIdx.x * blockDim.x + threadIdx.x;
    if (e < E) {
        int d = dst[e];
        int p = atomicAdd(&pcnt[d], 1);
        csrc[off[d] + p] = src[e];
    }
}

// Per-node edge softmax + aggregation + bias + lrelu(0.01) + head-mean.
// h: N x 384 (pre-attention features), out: N x 128
__global__ __launch_bounds__(384) void agg_kernel(
    const float* __restrict__ h, const float* __restrict__ el,
    const float* __restrict__ er, const int* __restrict__ off,
    const int* __restrict__ csrc, const float* __restrict__ bias,
    float* __restrict__ out, int N)
{
    int n = blockIdx.x;
    int tid = threadIdx.x;
    int hh = tid >> 7;
    int beg = off[n], end = off[n + 1];
    float erh = er[n * 3 + hh];

    // pass 1: max over incoming edges (each lane computes same m within a head)
    float m = -1e30f;
    for (int i = beg; i < end; ++i) {
        int s = csrc[i];
        float e = el[s * 3 + hh] + erh;
        e = (e < 0.f) ? 0.2f * e : e;
        m = fmaxf(m, e);
    }
    if (end == beg) m = 0.f;

    // pass 2: accumulate sum(w) and sum(w * h[src]) together
    float acc = 0.f, den = 0.f;
    for (int i = beg; i < end; ++i) {
        int s = csrc[i];
        float e = el[s * 3 + hh] + erh;
        e = (e < 0.f) ? 0.2f * e : e;
        float w = __expf(e - m);
        den += w;
        acc += w * h[(size_t)s * 384 + tid];
    }
    float v = acc / (den + 1e-9f) + bias[tid];
    v = (v < 0.f) ? 0.01f * v : v;       // nn.LeakyReLU(0.01)

    __shared__ float sm[384];
    sm[tid] = v;
    __syncthreads();
    if (tid < 128)
        out[(size_t)n * 128 + tid] =
            (sm[tid] + sm[tid + 128] + sm[tid + 256]) * (1.0f / 3.0f);
}

extern "C" void kernel_launch(void* const* d_in, const int* in_sizes, int n_in,
                              void* d_out, int out_size, void* d_ws, size_t ws_size,
                              hipStream_t stream)
{
    const float* in_feat = (const float*)d_in[0];
    const int*   src     = (const int*)d_in[1];
    const int*   dst     = (const int*)d_in[2];
    const float* W1  = (const float*)d_in[3];
    const float* al1 = (const float*)d_in[4];
    const float* ar1 = (const float*)d_in[5];
    const float* b1  = (const float*)d_in[6];
    const float* W2  = (const float*)d_in[7];
    const float* al2 = (const float*)d_in[8];
    const float* ar2 = (const float*)d_in[9];
    const float* b2  = (const float*)d_in[10];
    const float* lw1 = (const float*)d_in[11];
    const float* lb1 = (const float*)d_in[12];
    const float* lw2 = (const float*)d_in[13];
    const float* lb2 = (const float*)d_in[14];
    const float* lw3 = (const float*)d_in[15];
    const float* lb3 = (const float*)d_in[16];
    const float* lw4 = (const float*)d_in[17];
    const float* lb4 = (const float*)d_in[18];
    const float* lw5 = (const float*)d_in[19];
    const float* lb5 = (const float*)d_in[20];

    const int N = in_sizes[0] / 128;   // 50000
    const int E = in_sizes[1];         // 800000
    const int K = 128, H3 = 384;

    // workspace layout
    size_t o = 0;
    auto alloc = [&](size_t bytes) { size_t p = o; o = (o + bytes + 255) & ~(size_t)255; return p; };
    char* ws = (char*)d_ws;
    float* Abuf = (float*)(ws + alloc((size_t)N * H3 * 4));   // gemm out (N x 384)
    float* Bbuf = (float*)(ws + alloc((size_t)N * K * 4));    // node feats / mlp ping
    float* Cbuf = (float*)(ws + alloc((size_t)N * K * 4));    // mlp pong
    float* el   = (float*)(ws + alloc((size_t)N * 3 * 4));
    float* er   = (float*)(ws + alloc((size_t)N * 3 * 4));
    int*   cnt  = (int*)(ws + alloc((size_t)N * 4));
    int*   pcnt = (int*)(ws + alloc((size_t)N * 4));
    int*   off  = (int*)(ws + alloc((size_t)(N + 1) * 4));
    int*   csrc = (int*)(ws + alloc((size_t)E * 4));
    (void)ws_size;

    float* out = (float*)d_out;

    // ---- CSR build (same graph reused for both GAT layers)
    hipMemsetAsync(cnt, 0, (size_t)N * 4, stream);
    hipMemsetAsync(pcnt, 0, (size_t)N * 4, stream);
    hist_kernel<<<(E + 255) / 256, 256, 0, stream>>>(dst, cnt, E);
    scan_kernel<<<1, 1024, 0, stream>>>(cnt, off, N);
    scatter_kernel<<<(E + 255) / 256, 256, 0, stream>>>(src, dst, off, pcnt, csrc, E);

    dim3 blk(256);
    auto gemm = [&](const float* A, const float* W, const float* bias, float* C,
                    int M, int Nc, int flags) {
        dim3 grid((M + TILE - 1) / TILE, (Nc + TILE - 1) / TILE);
        gemm_kernel<<<grid, blk, 0, stream>>>(A, W, bias, C, M, Nc, K, flags);
    };

    // ---- GAT layer 1
    gemm(in_feat, W1, nullptr, Abuf, N, H3, 0);
    eler_kernel<<<N, 384, 0, stream>>>(Abuf, al1, ar1, el, er, N);
    agg_kernel<<<N, 384, 0, stream>>>(Abuf, el, er, off, csrc, b1, Bbuf, N);

    // ---- GAT layer 2
    gemm(Bbuf, W2, nullptr, Abuf, N, H3, 0);
    eler_kernel<<<N, 384, 0, stream>>>(Abuf, al2, ar2, el, er, N);
    agg_kernel<<<N, 384, 0, stream>>>(Abuf, el, er, off, csrc, b2, Cbuf, N);

    // ---- MLP head
    gemm(Cbuf, lw1, lb1, Bbuf, N, K, 3);
    gemm(Bbuf, lw2, lb2, Cbuf, N, K, 3);
    gemm(Cbuf, lw3, lb3, Bbuf, N, K, 3);
    gemm(Bbuf, lw4, lb4, Cbuf, N, K, 3);
    gemm(Cbuf, lw5, lb5, out, N, 6, 1);
}

// Round 2
// 1104.176 us; speedup vs baseline: 1.4958x; 1.4958x over previous
//
#include <hip/hip_runtime.h>
#include <hip/hip_bf16.h>

// ---------------------------------------------------------------------------
// GAT (2 GATConv layers + 5-layer MLP head), fp32.
// R1: edge softmax hoisted out of the wide agg kernel (mden_kernel computes
//     per-edge weights with 1 thread per (node,head)); agg is pure gather.
// ---------------------------------------------------------------------------

#define TILE 64
#define KC 16

// Generic fp32 GEMM: C[M x Nc] = A[M x 128] @ W[128 x Nc]  (+bias, +lrelu0.01)
// flags: 1 = add bias, 2 = leaky_relu(0.01)
__global__ __launch_bounds__(256) void gemm_kernel(
    const float* __restrict__ A, const float* __restrict__ W,
    const float* __restrict__ bias, float* __restrict__ C,
    int M, int Nc, int K, int flags)
{
    __shared__ float As[KC][TILE];   // [k][row]
    __shared__ float Ws[KC][TILE];   // [k][col]
    int tid = threadIdx.x;
    int tx = tid & 15, ty = tid >> 4;
    int rowBase = blockIdx.x * TILE;
    int colBase = blockIdx.y * TILE;
    float acc[4][4] = {};

    int la_r = tid >> 2;           // 0..63 tile row
    int la_c = (tid & 3) * 4;      // 0,4,8,12 k offset
    int lw_r = tid >> 4;           // 0..15 k row
    int lw_c = (tid & 15) * 4;     // 0..60 col offset
    bool ncAligned = ((Nc & 3) == 0);

    for (int k0 = 0; k0 < K; k0 += KC) {
        float4 av = make_float4(0.f, 0.f, 0.f, 0.f);
        int arow = rowBase + la_r;
        if (arow < M)
            av = *(const float4*)(A + (size_t)arow * K + k0 + la_c);
        As[la_c + 0][la_r] = av.x;
        As[la_c + 1][la_r] = av.y;
        As[la_c + 2][la_r] = av.z;
        As[la_c + 3][la_r] = av.w;
        float4 wv = make_float4(0.f, 0.f, 0.f, 0.f);
        int wc = colBase + lw_c;
        const float* wrow = W + (size_t)(k0 + lw_r) * Nc;
        if (ncAligned && wc + 3 < Nc) {
            wv = *(const float4*)(wrow + wc);
        } else {
            float t0 = (wc + 0 < Nc) ? wrow[wc + 0] : 0.f;
            float t1 = (wc + 1 < Nc) ? wrow[wc + 1] : 0.f;
            float t2 = (wc + 2 < Nc) ? wrow[wc + 2] : 0.f;
            float t3 = (wc + 3 < Nc) ? wrow[wc + 3] : 0.f;
            wv = make_float4(t0, t1, t2, t3);
        }
        *(float4*)&Ws[lw_r][lw_c] = wv;
        __syncthreads();
        #pragma unroll
        for (int kk = 0; kk < KC; ++kk) {
            float a[4], b[4];
            *(float4*)a = *(const float4*)&As[kk][ty * 4];
            *(float4*)b = *(const float4*)&Ws[kk][tx * 4];
            #pragma unroll
            for (int i = 0; i < 4; ++i)
                #pragma unroll
                for (int j = 0; j < 4; ++j)
                    acc[i][j] += a[i] * b[j];
        }
        __syncthreads();
    }
    #pragma unroll
    for (int i = 0; i < 4; ++i) {
        int r = rowBase + ty * 4 + i;
        if (r >= M) continue;
        #pragma unroll
        for (int j = 0; j < 4; ++j) {
            int c = colBase + tx * 4 + j;
            if (c >= Nc) continue;
            float v = acc[i][j];
            if (flags & 1) v += bias[c];
            if (flags & 2) v = (v < 0.f) ? 0.01f * v : v;
            C[(size_t)r * Nc + c] = v;
        }
    }
}

// el[n,h] = dot(h[n,h,:], al[h,:]); er likewise. h is N x 384.
__global__ __launch_bounds__(384) void eler_kernel(
    const float* __restrict__ h, const float* __restrict__ al,
    const float* __restrict__ ar, float* __restrict__ el,
    float* __restrict__ er, int N)
{
    int n = blockIdx.x;
    int tid = threadIdx.x;
    int hh = tid >> 7;
    int f = tid & 127;
    float x = h[(size_t)n * 384 + tid];
    __shared__ float sl[384], sr[384];
    sl[tid] = x * al[tid];
    sr[tid] = x * ar[tid];
    __syncthreads();
    for (int s = 64; s > 0; s >>= 1) {
        if (f < s) { sl[tid] += sl[tid + s]; sr[tid] += sr[tid + s]; }
        __syncthreads();
    }
    if (f == 0) {
        el[n * 3 + hh] = sl[tid];
        er[n * 3 + hh] = sr[tid];
    }
}

// CSR build: histogram of dst
__global__ void hist_kernel(const int* __restrict__ dst, int* __restrict__ cnt, int E)
{
    int e = blockIdx.x * blockDim.x + threadIdx.x;
    if (e < E) atomicAdd(&cnt[dst[e]], 1);
}

// Single-block exclusive scan: off[0..n] from cnt[0..n-1]
__global__ __launch_bounds__(1024) void scan_kernel(const int* __restrict__ cnt,
                                                    int* __restrict__ off, int n)
{
    __shared__ int carry;
    __shared__ int tmp[1024];
    if (threadIdx.x == 0) carry = 0;
    __syncthreads();
    for (int base = 0; base < n; base += 1024) {
        int i = base + threadIdx.x;
        int v = (i < n) ? cnt[i] : 0;
        tmp[threadIdx.x] = v;
        __syncthreads();
        for (int s = 1; s < 1024; s <<= 1) {
            int t = (threadIdx.x >= s) ? tmp[threadIdx.x - s] : 0;
            __syncthreads();
            tmp[threadIdx.x] += t;
            __syncthreads();
        }
        int excl = tmp[threadIdx.x] - v;
        if (i < n) off[i] = carry + excl;
        __syncthreads();
        if (threadIdx.x == 1023) carry += tmp[1023];
        __syncthreads();
    }
    if (threadIdx.x == 0) off[n] = carry;
}

// scatter edges into dst-sorted CSR (store src id)
__global__ void scatter_kernel(const int* __restrict__ src, const int* __restrict__ dst,
                               const int* __restrict__ off, int* __restrict__ pcnt,
                               int* __restrict__ csrc, int E)
{
    int e = blockIdx.x * blockDim.x + threadIdx.x;
    if (e < E) {
        int d = dst[e];
        int p = atomicAdd(&pcnt[d], 1);
        csrc[off[d] + p] = src[e];
    }
}

// One thread per (node, head): edge-softmax -> per-edge weight in CSR order.
// walpha[i*3+h] = exp(e_i - m) / (den + 1e-9)
__global__ __launch_bounds__(256) void mden_kernel(
    const float* __restrict__ el, const float* __restrict__ er,
    const int* __restrict__ off, const int* __restrict__ csrc,
    float* __restrict__ walpha, int N)
{
    int t = blockIdx.x * blockDim.x + threadIdx.x;
    if (t >= N * 3) return;
    int n = t / 3, hh = t - n * 3;
    int beg = off[n], end = off[n + 1];
    float erh = er[t];
    float m = -1e30f;
    for (int i = beg; i < end; ++i) {
        float e = el[csrc[i] * 3 + hh] + erh;
        e = (e < 0.f) ? 0.2f * e : e;
        m = fmaxf(m, e);
    }
    if (end == beg) return;
    float den = 0.f;
    for (int i = beg; i < end; ++i) {
        float e = el[csrc[i] * 3 + hh] + erh;
        e = (e < 0.f) ? 0.2f * e : e;
        den += __expf(e - m);
    }
    float r = 1.f / (den + 1e-9f);
    for (int i = beg; i < end; ++i) {
        float e = el[csrc[i] * 3 + hh] + erh;
        e = (e < 0.f) ? 0.2f * e : e;
        walpha[i * 3 + hh] = __expf(e - m) * r;
    }
}

// Pure weighted gather: out[n,f] = lrelu( sum_i w[i,h] * h[src_i, h, f] + b ),
// then mean over heads. Block = 384 threads = (head, feat).
__global__ __launch_bounds__(384) void agg_kernel(
    const float* __restrict__ h, const float* __restrict__ walpha,
    const int* __restrict__ off, const int* __restrict__ csrc,
    const float* __restrict__ bias, float* __restrict__ out, int N)
{
    int n = blockIdx.x;
    int tid = threadIdx.x;
    int hh = tid >> 7;
    int beg = off[n], end = off[n + 1];
    int deg = end - beg;

    __shared__ int   ssrc[64];
    __shared__ float sw[64 * 3];
    float acc = 0.f;

    for (int base = 0; base < deg; base += 64) {
        int cnt = min(64, deg - base);
        if (tid < cnt) ssrc[tid] = csrc[beg + base + tid];
        int j = tid - 128;
        if (j >= 0 && j < cnt * 3) sw[j] = walpha[(size_t)(beg + base) * 3 + j];
        __syncthreads();
        #pragma unroll 4
        for (int q = 0; q < cnt; ++q) {
            acc += sw[q * 3 + hh] * h[(size_t)ssrc[q] * 384 + tid];
        }
        __syncthreads();
    }
    float v = acc + bias[tid];
    v = (v < 0.f) ? 0.01f * v : v;       // nn.LeakyReLU(0.01)

    __shared__ float sm[384];
    sm[tid] = v;
    __syncthreads();
    if (tid < 128)
        out[(size_t)n * 128 + tid] =
            (sm[tid] + sm[tid + 128] + sm[tid + 256]) * (1.0f / 3.0f);
}

extern "C" void kernel_launch(void* const* d_in, const int* in_sizes, int n_in,
                              void* d_out, int out_size, void* d_ws, size_t ws_size,
                              hipStream_t stream)
{
    const float* in_feat = (const float*)d_in[0];
    const int*   src     = (const int*)d_in[1];
    const int*   dst     = (const int*)d_in[2];
    const float* W1  = (const float*)d_in[3];
    const float* al1 = (const float*)d_in[4];
    const float* ar1 = (const float*)d_in[5];
    const float* b1  = (const float*)d_in[6];
    const float* W2  = (const float*)d_in[7];
    const float* al2 = (const float*)d_in[8];
    const float* ar2 = (const float*)d_in[9];
    const float* b2  = (const float*)d_in[10];
    const float* lw1 = (const float*)d_in[11];
    const float* lb1 = (const float*)d_in[12];
    const float* lw2 = (const float*)d_in[13];
    const float* lb2 = (const float*)d_in[14];
    const float* lw3 = (const float*)d_in[15];
    const float* lb3 = (const float*)d_in[16];
    const float* lw4 = (const float*)d_in[17];
    const float* lb4 = (const float*)d_in[18];
    const float* lw5 = (const float*)d_in[19];
    const float* lb5 = (const float*)d_in[20];

    const int N = in_sizes[0] / 128;   // 50000
    const int E = in_sizes[1];         // 800000
    const int K = 128, H3 = 384;

    size_t o = 0;
    auto alloc = [&](size_t bytes) { size_t p = o; o = (o + bytes + 255) & ~(size_t)255; return p; };
    char* ws = (char*)d_ws;
    float* Abuf   = (float*)(ws + alloc((size_t)N * H3 * 4));   // gemm out (N x 384)
    float* Bbuf   = (float*)(ws + alloc((size_t)N * K * 4));
    float* Cbuf   = (float*)(ws + alloc((size_t)N * K * 4));
    float* el     = (float*)(ws + alloc((size_t)N * 3 * 4));
    float* er     = (float*)(ws + alloc((size_t)N * 3 * 4));
    int*   cnt    = (int*)(ws + alloc((size_t)N * 4));
    int*   pcnt   = (int*)(ws + alloc((size_t)N * 4));
    int*   off    = (int*)(ws + alloc((size_t)(N + 1) * 4));
    int*   csrc   = (int*)(ws + alloc((size_t)E * 4));
    float* walpha = (float*)(ws + alloc((size_t)E * 3 * 4));
    (void)ws_size;

    float* out = (float*)d_out;

    // ---- CSR build (same graph reused for both GAT layers)
    hipMemsetAsync(cnt, 0, (size_t)N * 4, stream);
    hipMemsetAsync(pcnt, 0, (size_t)N * 4, stream);
    hist_kernel<<<(E + 255) / 256, 256, 0, stream>>>(dst, cnt, E);
    scan_kernel<<<1, 1024, 0, stream>>>(cnt, off, N);
    scatter_kernel<<<(E + 255) / 256, 256, 0, stream>>>(src, dst, off, pcnt, csrc, E);

    dim3 blk(256);
    auto gemm = [&](const float* A, const float* W, const float* bias, float* C,
                    int M, int Nc, int flags) {
        dim3 grid((M + TILE - 1) / TILE, (Nc + TILE - 1) / TILE);
        gemm_kernel<<<grid, blk, 0, stream>>>(A, W, bias, C, M, Nc, K, flags);
    };
    int nh_blocks = (N * 3 + 255) / 256;

    // ---- GAT layer 1
    gemm(in_feat, W1, nullptr, Abuf, N, H3, 0);
    eler_kernel<<<N, 384, 0, stream>>>(Abuf, al1, ar1, el, er, N);
    mden_kernel<<<nh_blocks, 256, 0, stream>>>(el, er, off, csrc, walpha, N);
    agg_kernel<<<N, 384, 0, stream>>>(Abuf, walpha, off, csrc, b1, Bbuf, N);

    // ---- GAT layer 2
    gemm(Bbuf, W2, nullptr, Abuf, N, H3, 0);
    eler_kernel<<<N, 384, 0, stream>>>(Abuf, al2, ar2, el, er, N);
    mden_kernel<<<nh_blocks, 256, 0, stream>>>(el, er, off, csrc, walpha, N);
    agg_kernel<<<N, 384, 0, stream>>>(Abuf, walpha, off, csrc, b2, Cbuf, N);

    // ---- MLP head
    gemm(Cbuf, lw1, lb1, Bbuf, N, K, 3);
    gemm(Bbuf, lw2, lb2, Cbuf, N, K, 3);
    gemm(Cbuf, lw3, lb3, Bbuf, N, K, 3);
    gemm(Bbuf, lw4, lb4, Cbuf, N, K, 3);
    gemm(Cbuf, lw5, lb5, out, N, 6, 1);
}

// Round 3
// 1007.737 us; speedup vs baseline: 1.6389x; 1.0957x over previous
//
#include <hip/hip_runtime.h>
#include <hip/hip_bf16.h>

// ---------------------------------------------------------------------------
// GAT (2 GATConv layers + 5-layer MLP head).
// R1: CSR edge softmax split into mden (per node-head) + agg (pure gather).
// R3: all 7 GEMMs moved to bf16 MFMA with split-precision (x=hi+lo, 3 MFMAs)
//     for fp32-grade accuracy on the 2.5PF matrix pipe.
// ---------------------------------------------------------------------------

typedef __attribute__((ext_vector_type(8))) short short8;   // 8 bf16 = 4 VGPR
typedef __attribute__((ext_vector_type(4))) float float4v;  // MFMA C/D

__device__ inline short f2bf(float x) {
    union { float f; unsigned u; } v; v.f = x;
    unsigned r = v.u + 0x7FFFu + ((v.u >> 16) & 1u);
    return (short)(r >> 16);
}
__device__ inline float bf2f(short b) {
    union { float f; unsigned u; } v;
    v.u = ((unsigned)(unsigned short)b) << 16;
    return v.f;
}

#define BM 128
#define BN 64
#define BK 32
#define AST 40   // LDS row stride (shorts) for A tiles (pad 32->40)
#define WST 40   // LDS col stride (shorts) for B tiles

// C[M x Nc] = A[M x 128] @ W[128 x Nc] (+bias, +lrelu 0.01), split-bf16 MFMA.
// flags: 1 = add bias, 2 = leaky_relu(0.01)
__global__ __launch_bounds__(256) void gemm_mfma(
    const float* __restrict__ A, const float* __restrict__ W,
    const float* __restrict__ bias, float* __restrict__ C,
    int M, int Nc, int flags)
{
    __shared__ short AsH[BM * AST], AsL[BM * AST];
    __shared__ short WsH[BN * WST], WsL[BN * WST];

    int tid  = threadIdx.x;
    int lane = tid & 63, wave = tid >> 6;
    int rowBase = blockIdx.x * BM;
    int colBase = blockIdx.y * BN;
    int l15 = lane & 15, q = lane >> 4;

    float4v acc[2][4];
    #pragma unroll
    for (int mt = 0; mt < 2; ++mt)
        #pragma unroll
        for (int nt = 0; nt < 4; ++nt)
            acc[mt][nt] = (float4v){0.f, 0.f, 0.f, 0.f};

    // staging indices
    int ar = tid >> 3;            // 0..31 base row
    int ak = (tid & 7) * 4;       // k offset (floats)
    int wc = tid & 63;            // B col within tile
    int wk = (tid >> 6) * 8;      // B k offset (floats)
    int gcol = colBase + wc;

    for (int k0 = 0; k0 < 128; k0 += BK) {
        // ---- stage A tile (128 rows x 32 k), fp32 -> hi/lo bf16
        #pragma unroll
        for (int s = 0; s < 4; ++s) {
            int r = ar + s * 32;
            int grow = rowBase + r;
            float4 av = make_float4(0.f, 0.f, 0.f, 0.f);
            if (grow < M)
                av = *(const float4*)(A + (size_t)grow * 128 + k0 + ak);
            float xs[4] = {av.x, av.y, av.z, av.w};
            short hs[4], ls[4];
            #pragma unroll
            for (int j = 0; j < 4; ++j) {
                hs[j] = f2bf(xs[j]);
                ls[j] = f2bf(xs[j] - bf2f(hs[j]));
            }
            *(uint2*)&AsH[r * AST + ak] = *(uint2*)hs;
            *(uint2*)&AsL[r * AST + ak] = *(uint2*)ls;
        }
        // ---- stage B tile (32 k x 64 cols), transposed to [col][k]
        {
            short hs[8], ls[8];
            #pragma unroll
            for (int j = 0; j < 8; ++j) {
                float x = 0.f;
                if (gcol < Nc)
                    x = W[(size_t)(k0 + wk + j) * Nc + gcol];
                hs[j] = f2bf(x);
                ls[j] = f2bf(x - bf2f(hs[j]));
            }
            *(short8*)&WsH[wc * WST + wk] = *(short8*)hs;
            *(short8*)&WsL[wc * WST + wk] = *(short8*)ls;
        }
        __syncthreads();

        // ---- fragments + MFMA
        short8 aH[2], aL[2], bH[4], bL[4];
        #pragma unroll
        for (int mt = 0; mt < 2; ++mt) {
            int r = wave * 32 + mt * 16 + l15;
            aH[mt] = *(short8*)&AsH[r * AST + q * 8];
            aL[mt] = *(short8*)&AsL[r * AST + q * 8];
        }
        #pragma unroll
        for (int nt = 0; nt < 4; ++nt) {
            int c = nt * 16 + l15;
            bH[nt] = *(short8*)&WsH[c * WST + q * 8];
            bL[nt] = *(short8*)&WsL[c * WST + q * 8];
        }
        #pragma unroll
        for (int mt = 0; mt < 2; ++mt)
            #pragma unroll
            for (int nt = 0; nt < 4; ++nt) {
                acc[mt][nt] = __builtin_amdgcn_mfma_f32_16x16x32_bf16(
                    aH[mt], bH[nt], acc[mt][nt], 0, 0, 0);
                acc[mt][nt] = __builtin_amdgcn_mfma_f32_16x16x32_bf16(
                    aH[mt], bL[nt], acc[mt][nt], 0, 0, 0);
                acc[mt][nt] = __builtin_amdgcn_mfma_f32_16x16x32_bf16(
                    aL[mt], bH[nt], acc[mt][nt], 0, 0, 0);
            }
        __syncthreads();
    }

    // ---- epilogue: C/D layout col=lane&15, row=(lane>>4)*4+reg (m89)
    #pragma unroll
    for (int mt = 0; mt < 2; ++mt) {
        #pragma unroll
        for (int nt = 0; nt < 4; ++nt) {
            int c = colBase + nt * 16 + l15;
            if (c >= Nc) continue;
            float bv = (flags & 1) ? bias[c] : 0.f;
            #pragma unroll
            for (int i = 0; i < 4; ++i) {
                int r = rowBase + wave * 32 + mt * 16 + q * 4 + i;
                if (r >= M) continue;
                float v = acc[mt][nt][i] + bv;
                if (flags & 2) v = (v < 0.f) ? 0.01f * v : v;
                C[(size_t)r * Nc + c] = v;
            }
        }
    }
}

// el[n,h] = dot(h[n,h,:], al[h,:]); er likewise. h is N x 384.
__global__ __launch_bounds__(384) void eler_kernel(
    const float* __restrict__ h, const float* __restrict__ al,
    const float* __restrict__ ar, float* __restrict__ el,
    float* __restrict__ er, int N)
{
    int n = blockIdx.x;
    int tid = threadIdx.x;
    int hh = tid >> 7;
    int f = tid & 127;
    float x = h[(size_t)n * 384 + tid];
    __shared__ float sl[384], sr[384];
    sl[tid] = x * al[tid];
    sr[tid] = x * ar[tid];
    __syncthreads();
    for (int s = 64; s > 0; s >>= 1) {
        if (f < s) { sl[tid] += sl[tid + s]; sr[tid] += sr[tid + s]; }
        __syncthreads();
    }
    if (f == 0) {
        el[n * 3 + hh] = sl[tid];
        er[n * 3 + hh] = sr[tid];
    }
}

// CSR build: histogram of dst
__global__ void hist_kernel(const int* __restrict__ dst, int* __restrict__ cnt, int E)
{
    int e = blockIdx.x * blockDim.x + threadIdx.x;
    if (e < E) atomicAdd(&cnt[dst[e]], 1);
}

// Single-block exclusive scan: off[0..n] from cnt[0..n-1]
__global__ __launch_bounds__(1024) void scan_kernel(const int* __restrict__ cnt,
                                                    int* __restrict__ off, int n)
{
    __shared__ int carry;
    __shared__ int tmp[1024];
    if (threadIdx.x == 0) carry = 0;
    __syncthreads();
    for (int base = 0; base < n; base += 1024) {
        int i = base + threadIdx.x;
        int v = (i < n) ? cnt[i] : 0;
        tmp[threadIdx.x] = v;
        __syncthreads();
        for (int s = 1; s < 1024; s <<= 1) {
            int t = (threadIdx.x >= s) ? tmp[threadIdx.x - s] : 0;
            __syncthreads();
            tmp[threadIdx.x] += t;
            __syncthreads();
        }
        int excl = tmp[threadIdx.x] - v;
        if (i < n) off[i] = carry + excl;
        __syncthreads();
        if (threadIdx.x == 1023) carry += tmp[1023];
        __syncthreads();
    }
    if (threadIdx.x == 0) off[n] = carry;
}

// scatter edges into dst-sorted CSR (store src id)
__global__ void scatter_kernel(const int* __restrict__ src, const int* __restrict__ dst,
                               const int* __restrict__ off, int* __restrict__ pcnt,
                               int* __restrict__ csrc, int E)
{
    int e = blockIdx.x * blockDim.x + threadIdx.x;
    if (e < E) {
        int d = dst[e];
        int p = atomicAdd(&pcnt[d], 1);
        csrc[off[d] + p] = src[e];
    }
}

// One thread per (node, head): edge-softmax -> per-edge weight in CSR order.
__global__ __launch_bounds__(256) void mden_kernel(
    const float* __restrict__ el, const float* __restrict__ er,
    const int* __restrict__ off, const int* __restrict__ csrc,
    float* __restrict__ walpha, int N)
{
    int t = blockIdx.x * blockDim.x + threadIdx.x;
    if (t >= N * 3) return;
    int n = t / 3, hh = t - n * 3;
    int beg = off[n], end = off[n + 1];
    float erh = er[t];
    float m = -1e30f;
    for (int i = beg; i < end; ++i) {
        float e = el[csrc[i] * 3 + hh] + erh;
        e = (e < 0.f) ? 0.2f * e : e;
        m = fmaxf(m, e);
    }
    if (end == beg) return;
    float den = 0.f;
    for (int i = beg; i < end; ++i) {
        float e = el[csrc[i] * 3 + hh] + erh;
        e = (e < 0.f) ? 0.2f * e : e;
        den += __expf(e - m);
    }
    float r = 1.f / (den + 1e-9f);
    for (int i = beg; i < end; ++i) {
        float e = el[csrc[i] * 3 + hh] + erh;
        e = (e < 0.f) ? 0.2f * e : e;
        walpha[i * 3 + hh] = __expf(e - m) * r;
    }
}

// Pure weighted gather + bias + lrelu + head-mean. Block = 384 = (head, feat).
__global__ __launch_bounds__(384) void agg_kernel(
    const float* __restrict__ h, const float* __restrict__ walpha,
    const int* __restrict__ off, const int* __restrict__ csrc,
    const float* __restrict__ bias, float* __restrict__ out, int N)
{
    int n = blockIdx.x;
    int tid = threadIdx.x;
    int hh = tid >> 7;
    int beg = off[n], end = off[n + 1];
    int deg = end - beg;

    __shared__ int   ssrc[64];
    __shared__ float sw[64 * 3];
    float acc = 0.f;

    for (int base = 0; base < deg; base += 64) {
        int cnt = min(64, deg - base);
        if (tid < cnt) ssrc[tid] = csrc[beg + base + tid];
        int j = tid - 128;
        if (j >= 0 && j < cnt * 3) sw[j] = walpha[(size_t)(beg + base) * 3 + j];
        __syncthreads();
        #pragma unroll 4
        for (int qq = 0; qq < cnt; ++qq) {
            acc += sw[qq * 3 + hh] * h[(size_t)ssrc[qq] * 384 + tid];
        }
        __syncthreads();
    }
    float v = acc + bias[tid];
    v = (v < 0.f) ? 0.01f * v : v;       // nn.LeakyReLU(0.01)

    __shared__ float sm[384];
    sm[tid] = v;
    __syncthreads();
    if (tid < 128)
        out[(size_t)n * 128 + tid] =
            (sm[tid] + sm[tid + 128] + sm[tid + 256]) * (1.0f / 3.0f);
}

extern "C" void kernel_launch(void* const* d_in, const int* in_sizes, int n_in,
                              void* d_out, int out_size, void* d_ws, size_t ws_size,
                              hipStream_t stream)
{
    const float* in_feat = (const float*)d_in[0];
    const int*   src     = (const int*)d_in[1];
    const int*   dst     = (const int*)d_in[2];
    const float* W1  = (const float*)d_in[3];
    const float* al1 = (const float*)d_in[4];
    const float* ar1 = (const float*)d_in[5];
    const float* b1  = (const float*)d_in[6];
    const float* W2  = (const float*)d_in[7];
    const float* al2 = (const float*)d_in[8];
    const float* ar2 = (const float*)d_in[9];
    const float* b2  = (const float*)d_in[10];
    const float* lw1 = (const float*)d_in[11];
    const float* lb1 = (const float*)d_in[12];
    const float* lw2 = (const float*)d_in[13];
    const float* lb2 = (const float*)d_in[14];
    const float* lw3 = (const float*)d_in[15];
    const float* lb3 = (const float*)d_in[16];
    const float* lw4 = (const float*)d_in[17];
    const float* lb4 = (const float*)d_in[18];
    const float* lw5 = (const float*)d_in[19];
    const float* lb5 = (const float*)d_in[20];

    const int N = in_sizes[0] / 128;   // 50000
    const int E = in_sizes[1];         // 800000
    const int K = 128, H3 = 384;

    size_t o = 0;
    auto alloc = [&](size_t bytes) { size_t p = o; o = (o + bytes + 255) & ~(size_t)255; return p; };
    char* ws = (char*)d_ws;
    float* Abuf   = (float*)(ws + alloc((size_t)N * H3 * 4));   // gemm out (N x 384)
    float* Bbuf   = (float*)(ws + alloc((size_t)N * K * 4));
    float* Cbuf   = (float*)(ws + alloc((size_t)N * K * 4));
    float* el     = (float*)(ws + alloc((size_t)N * 3 * 4));
    float* er     = (float*)(ws + alloc((size_t)N * 3 * 4));
    int*   cnt    = (int*)(ws + alloc((size_t)N * 4));
    int*   pcnt   = (int*)(ws + alloc((size_t)N * 4));
    int*   off    = (int*)(ws + alloc((size_t)(N + 1) * 4));
    int*   csrc   = (int*)(ws + alloc((size_t)E * 4));
    float* walpha = (float*)(ws + alloc((size_t)E * 3 * 4));
    (void)ws_size;

    float* out = (float*)d_out;

    // ---- CSR build (same graph reused for both GAT layers)
    hipMemsetAsync(cnt, 0, (size_t)N * 4, stream);
    hipMemsetAsync(pcnt, 0, (size_t)N * 4, stream);
    hist_kernel<<<(E + 255) / 256, 256, 0, stream>>>(dst, cnt, E);
    scan_kernel<<<1, 1024, 0, stream>>>(cnt, off, N);
    scatter_kernel<<<(E + 255) / 256, 256, 0, stream>>>(src, dst, off, pcnt, csrc, E);

    auto gemm = [&](const float* A, const float* W, const float* bias, float* C,
                    int M, int Nc, int flags) {
        dim3 grid((M + BM - 1) / BM, (Nc + BN - 1) / BN);
        gemm_mfma<<<grid, 256, 0, stream>>>(A, W, bias, C, M, Nc, flags);
    };
    int nh_blocks = (N * 3 + 255) / 256;

    // ---- GAT layer 1
    gemm(in_feat, W1, nullptr, Abuf, N, H3, 0);
    eler_kernel<<<N, 384, 0, stream>>>(Abuf, al1, ar1, el, er, N);
    mden_kernel<<<nh_blocks, 256, 0, stream>>>(el, er, off, csrc, walpha, N);
    agg_kernel<<<N, 384, 0, stream>>>(Abuf, walpha, off, csrc, b1, Bbuf, N);

    // ---- GAT layer 2
    gemm(Bbuf, W2, nullptr, Abuf, N, H3, 0);
    eler_kernel<<<N, 384, 0, stream>>>(Abuf, al2, ar2, el, er, N);
    mden_kernel<<<nh_blocks, 256, 0, stream>>>(el, er, off, csrc, walpha, N);
    agg_kernel<<<N, 384, 0, stream>>>(Abuf, walpha, off, csrc, b2, Cbuf, N);

    // ---- MLP head
    gemm(Cbuf, lw1, lb1, Bbuf, N, K, 3);
    gemm(Bbuf, lw2, lb2, Cbuf, N, K, 3);
    gemm(Cbuf, lw3, lb3, Bbuf, N, K, 3);
    gemm(Bbuf, lw4, lb4, Cbuf, N, K, 3);
    gemm(Cbuf, lw5, lb5, out, N, 6, 1);
}

// Round 4
// 830.442 us; speedup vs baseline: 1.9888x; 1.2135x over previous
//
#include <hip/hip_runtime.h>
#include <hip/hip_bf16.h>

// ---------------------------------------------------------------------------
// GAT (2 GATConv + 5-layer MLP), MI355X.
// R4: bf16 hi/lo planes carried end-to-end (split-bf16 MFMA, 3 terms);
//     el/er fused into GAT GEMM epilogue; agg gathers hi-plane only (half
//     traffic); hierarchical scan replaces serial single-block scan.
// ---------------------------------------------------------------------------

typedef __attribute__((ext_vector_type(8))) short short8;   // 8 bf16 = 4 VGPR
typedef __attribute__((ext_vector_type(4))) float float4v;  // MFMA C/D

__device__ inline short f2bf(float x) {
    union { float f; unsigned u; } v; v.f = x;
    unsigned r = v.u + 0x7FFFu + ((v.u >> 16) & 1u);   // RNE
    return (short)(r >> 16);
}
__device__ inline float bf2f(short b) {
    union { float f; unsigned u; } v;
    v.u = ((unsigned)(unsigned short)b) << 16;
    return v.f;
}
__device__ inline short8 zero8() { short8 z = {0,0,0,0,0,0,0,0}; return z; }

#define BM 128
#define BN 128
#define BK 32
#define LSTR 40   // LDS row stride in shorts (80 B, 16B-aligned, breaks pow2)

// ---------------------------------------------------------------------------
// Split fp32 x into hi/lo bf16 planes (vectorized by 4). n4 = n/4.
__global__ void conv_split(const float* __restrict__ x, short* __restrict__ hi,
                           short* __restrict__ lo, int n4)
{
    int i = blockIdx.x * blockDim.x + threadIdx.x;
    if (i >= n4) return;
    float4 v = *(const float4*)(x + (size_t)i * 4);
    float xs[4] = {v.x, v.y, v.z, v.w};
    short hs[4], ls[4];
    #pragma unroll
    for (int j = 0; j < 4; ++j) {
        hs[j] = f2bf(xs[j]);
        ls[j] = f2bf(xs[j] - bf2f(hs[j]));
    }
    *(uint2*)(hi + (size_t)i * 4) = *(uint2*)hs;
    *(uint2*)(lo + (size_t)i * 4) = *(uint2*)ls;
}

// Weight: fp32 [K][Nc] -> transposed bf16 hi/lo planes [Nc][K]. Run once, tiny.
__global__ void convw_t(const float* __restrict__ w, short* __restrict__ th,
                        short* __restrict__ tl, int K, int Nc)
{
    int i = blockIdx.x * blockDim.x + threadIdx.x;
    if (i >= K * Nc) return;
    int k = i / Nc, c = i - k * Nc;
    float v = w[i];
    short h = f2bf(v);
    th[(size_t)c * K + k] = h;
    tl[(size_t)c * K + k] = f2bf(v - bf2f(h));
}

// ---------------------------------------------------------------------------
// GEMM: C[M x Nc] = A[M x 128] @ W[128 x Nc], A as hi/lo bf16 planes [M][128],
// W as transposed hi/lo planes [Nc][128]. Split-bf16: hh + hl + lh MFMAs.
// flags: 1 bias, 2 lrelu(0.01), 4 fused el/er (head = blockIdx.x; Nc=384),
//        8 write fp32 C, 16 write hi plane, 32 write lo plane.
__global__ __launch_bounds__(256) void gemm_mfma(
    const short* __restrict__ Ahi, const short* __restrict__ Alo,
    const short* __restrict__ Bth, const short* __restrict__ Btl,
    const float* __restrict__ bias,
    float* __restrict__ Cf, short* __restrict__ Chi, short* __restrict__ Clo,
    float* __restrict__ el, float* __restrict__ er,
    const float* __restrict__ al, const float* __restrict__ ar,
    int M, int Nc, int flags)
{
    __shared__ short Ah[BM * LSTR], Al_[BM * LSTR];
    __shared__ short Bh[BN * LSTR], Bl_[BN * LSTR];

    int tid = threadIdx.x, lane = tid & 63, wave = tid >> 6;
    int l15 = lane & 15, q = lane >> 4;
    int rowBase = blockIdx.y * BM, colBase = blockIdx.x * BN;

    float4v acc[2][8];
    #pragma unroll
    for (int mt = 0; mt < 2; ++mt)
        #pragma unroll
        for (int nt = 0; nt < 8; ++nt)
            acc[mt][nt] = (float4v){0.f, 0.f, 0.f, 0.f};

    for (int k0 = 0; k0 < 128; k0 += BK) {
        // stage A (128 rows x 32 k) and B (128 cols x 32 k): pure 16B copies
        #pragma unroll
        for (int s = 0; s < 2; ++s) {
            int c = tid + s * 256;
            int r = c >> 2, kq = (c & 3) * 8;
            int gr = rowBase + r;
            short8 vh = zero8(), vl = zero8();
            if (gr < M) {
                vh = *(const short8*)(Ahi + (size_t)gr * 128 + k0 + kq);
                vl = *(const short8*)(Alo + (size_t)gr * 128 + k0 + kq);
            }
            *(short8*)&Ah[r * LSTR + kq]  = vh;
            *(short8*)&Al_[r * LSTR + kq] = vl;
            int gc = colBase + r;
            short8 wh = zero8(), wl = zero8();
            if (gc < Nc) {
                wh = *(const short8*)(Bth + (size_t)gc * 128 + k0 + kq);
                wl = *(const short8*)(Btl + (size_t)gc * 128 + k0 + kq);
            }
            *(short8*)&Bh[r * LSTR + kq]  = wh;
            *(short8*)&Bl_[r * LSTR + kq] = wl;
        }
        __syncthreads();

        short8 aH[2], aL2[2];
        #pragma unroll
        for (int mt = 0; mt < 2; ++mt) {
            int off = (wave * 32 + mt * 16 + l15) * LSTR + q * 8;
            aH[mt]  = *(short8*)&Ah[off];
            aL2[mt] = *(short8*)&Al_[off];
        }
        #pragma unroll
        for (int nt = 0; nt < 8; ++nt) {
            int off = (nt * 16 + l15) * LSTR + q * 8;
            short8 bH = *(short8*)&Bh[off];
            short8 bL = *(short8*)&Bl_[off];
            #pragma unroll
            for (int mt = 0; mt < 2; ++mt) {
                acc[mt][nt] = __builtin_amdgcn_mfma_f32_16x16x32_bf16(aH[mt], bH, acc[mt][nt], 0, 0, 0);
                acc[mt][nt] = __builtin_amdgcn_mfma_f32_16x16x32_bf16(aH[mt], bL, acc[mt][nt], 0, 0, 0);
                acc[mt][nt] = __builtin_amdgcn_mfma_f32_16x16x32_bf16(aL2[mt], bH, acc[mt][nt], 0, 0, 0);
            }
        }
        __syncthreads();
    }

    // ---- fused el/er (GAT): head = blockIdx.x, cols within head = nt*16+l15
    if (flags & 4) {
        const float* alh = al + colBase;   // al is [3][128] flat; colBase = head*128
        const float* arh = ar + colBase;
        float pel[2][4] = {}, per_[2][4] = {};
        #pragma unroll
        for (int nt = 0; nt < 8; ++nt) {
            float av = alh[nt * 16 + l15];
            float rv = arh[nt * 16 + l15];
            #pragma unroll
            for (int mt = 0; mt < 2; ++mt)
                #pragma unroll
                for (int i = 0; i < 4; ++i) {
                    pel[mt][i]  += acc[mt][nt][i] * av;
                    per_[mt][i] += acc[mt][nt][i] * rv;
                }
        }
        #pragma unroll
        for (int mask = 1; mask < 16; mask <<= 1)
            #pragma unroll
            for (int mt = 0; mt < 2; ++mt)
                #pragma unroll
                for (int i = 0; i < 4; ++i) {
                    pel[mt][i]  += __shfl_xor(pel[mt][i], mask);
                    per_[mt][i] += __shfl_xor(per_[mt][i], mask);
                }
        if (l15 == 0) {
            #pragma unroll
            for (int mt = 0; mt < 2; ++mt)
                #pragma unroll
                for (int i = 0; i < 4; ++i) {
                    int r = rowBase + wave * 32 + mt * 16 + q * 4 + i;
                    if (r < M) {
                        el[r * 3 + blockIdx.x] = pel[mt][i];
                        er[r * 3 + blockIdx.x] = per_[mt][i];
                    }
                }
        }
    }

    // ---- C write: col = l15 within tile, row = q*4+i (verified layout)
    #pragma unroll
    for (int mt = 0; mt < 2; ++mt) {
        #pragma unroll
        for (int nt = 0; nt < 8; ++nt) {
            int c = colBase + nt * 16 + l15;
            if (c >= Nc) continue;
            float bv = (flags & 1) ? bias[c] : 0.f;
            #pragma unroll
            for (int i = 0; i < 4; ++i) {
                int r = rowBase + wave * 32 + mt * 16 + q * 4 + i;
                if (r >= M) continue;
                float v = acc[mt][nt][i] + bv;
                if (flags & 2) v = (v < 0.f) ? 0.01f * v : v;
                size_t idx = (size_t)r * Nc + c;
                if (flags & 8)  Cf[idx] = v;
                if (flags & 16) {
                    short hh = f2bf(v);
                    Chi[idx] = hh;
                    if (flags & 32) Clo[idx] = f2bf(v - bf2f(hh));
                }
            }
        }
    }
}

// ---------------------------------------------------------------------------
// CSR build
__global__ void hist_kernel(const int* __restrict__ dst, int* __restrict__ cnt, int E)
{
    int e = blockIdx.x * blockDim.x + threadIdx.x;
    if (e < E) atomicAdd(&cnt[dst[e]], 1);
}

// per-1024-chunk exclusive scan; chunk totals to bsum
__global__ __launch_bounds__(1024) void scan_block(const int* __restrict__ cnt,
                                                   int* __restrict__ off,
                                                   int* __restrict__ bsum, int n)
{
    __shared__ int tmp[1024];
    int tid = threadIdx.x;
    int i = blockIdx.x * 1024 + tid;
    int v = (i < n) ? cnt[i] : 0;
    tmp[tid] = v;
    __syncthreads();
    for (int s = 1; s < 1024; s <<= 1) {
        int t = (tid >= s) ? tmp[tid - s] : 0;
        __syncthreads();
        tmp[tid] += t;
        __syncthreads();
    }
    if (i < n) off[i] = tmp[tid] - v;
    if (tid == 1023) bsum[blockIdx.x] = tmp[1023];
}

// single block: exclusive-scan bsum[0..nb), bsum[nb] = total (nb <= 256)
__global__ __launch_bounds__(256) void scan_tops(int* __restrict__ bsum, int nb)
{
    __shared__ int tmp[256];
    int tid = threadIdx.x;
    int v = (tid < nb) ? bsum[tid] : 0;
    tmp[tid] = v;
    __syncthreads();
    for (int s = 1; s < 256; s <<= 1) {
        int t = (tid >= s) ? tmp[tid - s] : 0;
        __syncthreads();
        tmp[tid] += t;
        __syncthreads();
    }
    if (tid < nb) bsum[tid] = tmp[tid] - v;
    if (tid == 0) bsum[nb] = tmp[255];
}

__global__ void scan_add(int* __restrict__ off, const int* __restrict__ bsum,
                         int n, int nb)
{
    int i = blockIdx.x * blockDim.x + threadIdx.x;
    if (i < n) off[i] += bsum[i >> 10];
    if (i == 0) off[n] = bsum[nb];
}

__global__ void scatter_kernel(const int* __restrict__ src, const int* __restrict__ dst,
                               const int* __restrict__ off, int* __restrict__ pcnt,
                               int* __restrict__ csrc, int E)
{
    int e = blockIdx.x * blockDim.x + threadIdx.x;
    if (e < E) {
        int d = dst[e];
        int p = atomicAdd(&pcnt[d], 1);
        csrc[off[d] + p] = src[e];
    }
}

// ---------------------------------------------------------------------------
// One thread per (node, head): edge softmax -> per-edge weight in CSR order.
__global__ __launch_bounds__(256) void mden_kernel(
    const float* __restrict__ el, const float* __restrict__ er,
    const int* __restrict__ off, const int* __restrict__ csrc,
    float* __restrict__ walpha, int N)
{
    int t = blockIdx.x * blockDim.x + threadIdx.x;
    if (t >= N * 3) return;
    int n = t / 3, hh = t - n * 3;
    int beg = off[n], end = off[n + 1];
    float erh = er[t];
    float m = -1e30f;
    for (int i = beg; i < end; ++i) {
        float e = el[csrc[i] * 3 + hh] + erh;
        e = (e < 0.f) ? 0.2f * e : e;
        m = fmaxf(m, e);
    }
    if (end == beg) return;
    float den = 0.f;
    for (int i = beg; i < end; ++i) {
        float e = el[csrc[i] * 3 + hh] + erh;
        e = (e < 0.f) ? 0.2f * e : e;
        den += __expf(e - m);
    }
    float r = 1.f / (den + 1e-9f);
    for (int i = beg; i < end; ++i) {
        float e = el[csrc[i] * 3 + hh] + erh;
        e = (e < 0.f) ? 0.2f * e : e;
        walpha[i * 3 + hh] = __expf(e - m) * r;
    }
}

// ---------------------------------------------------------------------------
// Weighted gather over bf16-hi h plane + bias + lrelu + head-mean.
// Writes hi/lo bf16 planes (N x 128 each) for the next GEMM.
__global__ __launch_bounds__(384) void agg_kernel(
    const short* __restrict__ h, const float* __restrict__ walpha,
    const int* __restrict__ off, const int* __restrict__ csrc,
    const float* __restrict__ bias,
    short* __restrict__ outH, short* __restrict__ outL, int N)
{
    int n = blockIdx.x;
    int tid = threadIdx.x;
    int hh = tid >> 7;
    int beg = off[n], end = off[n + 1];
    int deg = end - beg;

    __shared__ int   ssrc[64];
    __shared__ float sw[64 * 3];
    float acc = 0.f;

    for (int base = 0; base < deg; base += 64) {
        int cnt = min(64, deg - base);
        if (tid < cnt) ssrc[tid] = csrc[beg + base + tid];
        int j = tid - 128;
        if (j >= 0 && j < cnt * 3) sw[j] = walpha[(size_t)(beg + base) * 3 + j];
        __syncthreads();
        #pragma unroll 4
        for (int qq = 0; qq < cnt; ++qq) {
            float hv = bf2f(h[(size_t)ssrc[qq] * 384 + tid]);
            acc += sw[qq * 3 + hh] * hv;
        }
        __syncthreads();
    }
    float v = acc + bias[tid];
    v = (v < 0.f) ? 0.01f * v : v;

    __shared__ float sm[384];
    sm[tid] = v;
    __syncthreads();
    if (tid < 128) {
        float v3 = (sm[tid] + sm[tid + 128] + sm[tid + 256]) * (1.0f / 3.0f);
        short hv = f2bf(v3);
        outH[(size_t)n * 128 + tid] = hv;
        outL[(size_t)n * 128 + tid] = f2bf(v3 - bf2f(hv));
    }
}

// ---------------------------------------------------------------------------
extern "C" void kernel_launch(void* const* d_in, const int* in_sizes, int n_in,
                              void* d_out, int out_size, void* d_ws, size_t ws_size,
                              hipStream_t stream)
{
    const float* in_feat = (const float*)d_in[0];
    const int*   src     = (const int*)d_in[1];
    const int*   dst     = (const int*)d_in[2];
    const float* W1  = (const float*)d_in[3];
    const float* al1 = (const float*)d_in[4];
    const float* ar1 = (const float*)d_in[5];
    const float* b1  = (const float*)d_in[6];
    const float* W2  = (const float*)d_in[7];
    const float* al2 = (const float*)d_in[8];
    const float* ar2 = (const float*)d_in[9];
    const float* b2  = (const float*)d_in[10];
    const float* lw1 = (const float*)d_in[11];
    const float* lb1 = (const float*)d_in[12];
    const float* lw2 = (const float*)d_in[13];
    const float* lb2 = (const float*)d_in[14];
    const float* lw3 = (const float*)d_in[15];
    const float* lb3 = (const float*)d_in[16];
    const float* lw4 = (const float*)d_in[17];
    const float* lb4 = (const float*)d_in[18];
    const float* lw5 = (const float*)d_in[19];
    const float* lb5 = (const float*)d_in[20];

    const int N = in_sizes[0] / 128;   // 50000
    const int E = in_sizes[1];         // 800000

    size_t o = 0;
    auto alloc = [&](size_t bytes) { size_t p = o; o = (o + bytes + 255) & ~(size_t)255; return p; };
    char* ws = (char*)d_ws;
    short* P1h = (short*)(ws + alloc((size_t)N * 128 * 2));
    short* P1l = (short*)(ws + alloc((size_t)N * 128 * 2));
    short* P2h = (short*)(ws + alloc((size_t)N * 128 * 2));
    short* P2l = (short*)(ws + alloc((size_t)N * 128 * 2));
    short* AbH = (short*)(ws + alloc((size_t)N * 384 * 2));   // GAT gemm out, hi only
    float* el  = (float*)(ws + alloc((size_t)N * 3 * 4));
    float* er  = (float*)(ws + alloc((size_t)N * 3 * 4));
    int*   cnt  = (int*)(ws + alloc((size_t)N * 4));
    int*   pcnt = (int*)(ws + alloc((size_t)N * 4));
    int*   off  = (int*)(ws + alloc((size_t)(N + 1) * 4));
    int*   bsum = (int*)(ws + alloc((size_t)4096));
    int*   csrc = (int*)(ws + alloc((size_t)E * 4));
    float* walpha = (float*)(ws + alloc((size_t)E * 3 * 4));
    short* w1th = (short*)(ws + alloc((size_t)384 * 128 * 2));
    short* w1tl = (short*)(ws + alloc((size_t)384 * 128 * 2));
    short* w2th = (short*)(ws + alloc((size_t)384 * 128 * 2));
    short* w2tl = (short*)(ws + alloc((size_t)384 * 128 * 2));
    short* l1th = (short*)(ws + alloc((size_t)128 * 128 * 2));
    short* l1tl = (short*)(ws + alloc((size_t)128 * 128 * 2));
    short* l2th = (short*)(ws + alloc((size_t)128 * 128 * 2));
    short* l2tl = (short*)(ws + alloc((size_t)128 * 128 * 2));
    short* l3th = (short*)(ws + alloc((size_t)128 * 128 * 2));
    short* l3tl = (short*)(ws + alloc((size_t)128 * 128 * 2));
    short* l4th = (short*)(ws + alloc((size_t)128 * 128 * 2));
    short* l4tl = (short*)(ws + alloc((size_t)128 * 128 * 2));
    short* l5th = (short*)(ws + alloc((size_t)6 * 128 * 2));
    short* l5tl = (short*)(ws + alloc((size_t)6 * 128 * 2));
    (void)ws_size;

    float* out = (float*)d_out;

    // ---- input/weight conversions
    conv_split<<<(N * 128 / 4 + 255) / 256, 256, 0, stream>>>(in_feat, P1h, P1l, N * 128 / 4);
    convw_t<<<(128 * 384 + 255) / 256, 256, 0, stream>>>(W1, w1th, w1tl, 128, 384);
    convw_t<<<(128 * 384 + 255) / 256, 256, 0, stream>>>(W2, w2th, w2tl, 128, 384);
    convw_t<<<(128 * 128 + 255) / 256, 256, 0, stream>>>(lw1, l1th, l1tl, 128, 128);
    convw_t<<<(128 * 128 + 255) / 256, 256, 0, stream>>>(lw2, l2th, l2tl, 128, 128);
    convw_t<<<(128 * 128 + 255) / 256, 256, 0, stream>>>(lw3, l3th, l3tl, 128, 128);
    convw_t<<<(128 * 128 + 255) / 256, 256, 0, stream>>>(lw4, l4th, l4tl, 128, 128);
    convw_t<<<(128 * 6 + 255) / 256, 256, 0, stream>>>(lw5, l5th, l5tl, 128, 6);

    // ---- CSR build
    hipMemsetAsync(cnt, 0, (size_t)N * 4, stream);
    hipMemsetAsync(pcnt, 0, (size_t)N * 4, stream);
    hist_kernel<<<(E + 255) / 256, 256, 0, stream>>>(dst, cnt, E);
    int nb = (N + 1023) / 1024;
    scan_block<<<nb, 1024, 0, stream>>>(cnt, off, bsum, N);
    scan_tops<<<1, 256, 0, stream>>>(bsum, nb);
    scan_add<<<(N + 255) / 256, 256, 0, stream>>>(off, bsum, N, nb);
    scatter_kernel<<<(E + 255) / 256, 256, 0, stream>>>(src, dst, off, pcnt, csrc, E);

    int RB = (N + BM - 1) / BM;
    auto gemm = [&](const short* ah, const short* alo, const short* bth, const short* btl,
                    const float* bias, float* cf, short* chi, short* clo,
                    float* elp, float* erp, const float* alp, const float* arp,
                    int Nc, int flags) {
        dim3 grid((Nc + BN - 1) / BN, RB);
        gemm_mfma<<<grid, 256, 0, stream>>>(ah, alo, bth, btl, bias, cf, chi, clo,
                                            elp, erp, alp, arp, N, Nc, flags);
    };
    int nh_blocks = (N * 3 + 255) / 256;

    // ---- GAT layer 1
    gemm(P1h, P1l, w1th, w1tl, nullptr, nullptr, AbH, nullptr, el, er, al1, ar1, 384, 4 | 16);
    mden_kernel<<<nh_blocks, 256, 0, stream>>>(el, er, off, csrc, walpha, N);
    agg_kernel<<<N, 384, 0, stream>>>(AbH, walpha, off, csrc, b1, P2h, P2l, N);

    // ---- GAT layer 2
    gemm(P2h, P2l, w2th, w2tl, nullptr, nullptr, AbH, nullptr, el, er, al2, ar2, 384, 4 | 16);
    mden_kernel<<<nh_blocks, 256, 0, stream>>>(el, er, off, csrc, walpha, N);
    agg_kernel<<<N, 384, 0, stream>>>(AbH, walpha, off, csrc, b2, P1h, P1l, N);

    // ---- MLP head (bias + lrelu fused; hi/lo planes ping-pong)
    gemm(P1h, P1l, l1th, l1tl, lb1, nullptr, P2h, P2l, nullptr, nullptr, nullptr, nullptr, 128, 1 | 2 | 16 | 32);
    gemm(P2h, P2l, l2th, l2tl, lb2, nullptr, P1h, P1l, nullptr, nullptr, nullptr, nullptr, 128, 1 | 2 | 16 | 32);
    gemm(P1h, P1l, l3th, l3tl, lb3, nullptr, P2h, P2l, nullptr, nullptr, nullptr, nullptr, 128, 1 | 2 | 16 | 32);
    gemm(P2h, P2l, l4th, l4tl, lb4, nullptr, P1h, P1l, nullptr, nullptr, nullptr, nullptr, 128, 1 | 2 | 16 | 32);
    gemm(P1h, P1l, l5th, l5tl, lb5, out, nullptr, nullptr, nullptr, nullptr, nullptr, nullptr, 6, 1 | 8);
}